// Round 3
// baseline (187.513 us; speedup 1.0000x reference)
//
#include <hip/hip_runtime.h>
#include <stdint.h>

// Problem constants
#define B_  1024
#define D_  512
#define K_  255
#define L_  256
#define C_  80

typedef __attribute__((ext_vector_type(8))) short bf16x8;
typedef __attribute__((ext_vector_type(4))) float f32x4;
typedef __attribute__((ext_vector_type(8))) short short8;

// async global->LDS, 16B per lane; dst must be wave-uniform base + lane*16.
#define GLD(gsrc, ldst) \
  __builtin_amdgcn_global_load_lds((const __attribute__((address_space(1))) void*)(gsrc), \
                                   (__attribute__((address_space(3))) void*)(ldst), 16, 0, 0)

__device__ __forceinline__ short cvt_bf16(float f) {
    unsigned u = __float_as_uint(f);
    u += 0x7FFFu + ((u >> 16) & 1u);
    return (short)(u >> 16);
}

// ---------------------------------------------------------------------------
// Kernel 1: convert W (20480x512) + x (1024x512) fp32->bf16, AND normalize
// ne rows -> bf16 neb (256 rows; row 255 zeroed).
// blocks [0,2048): grid-stride W/x convert. blocks [2048,2304): ne rows.
// ---------------------------------------------------------------------------
__global__ __launch_bounds__(256) void convert_kernel(const float* __restrict__ w,
                                                      const float* __restrict__ x,
                                                      const float* __restrict__ ne,
                                                      short* __restrict__ wb,
                                                      short* __restrict__ xb,
                                                      short* __restrict__ neb) {
    __shared__ float red[256];
    const int tid = threadIdx.x;
    if (blockIdx.x < 2048) {
        size_t i0 = (size_t)blockIdx.x * 256 + tid;
        const size_t stride = 2048u * 256u;
        for (size_t v = i0; v < 1310720u; v += stride) {
            float4 a = ((const float4*)w)[v * 2];
            float4 b = ((const float4*)w)[v * 2 + 1];
            short8 o;
            o[0] = cvt_bf16(a.x); o[1] = cvt_bf16(a.y); o[2] = cvt_bf16(a.z); o[3] = cvt_bf16(a.w);
            o[4] = cvt_bf16(b.x); o[5] = cvt_bf16(b.y); o[6] = cvt_bf16(b.z); o[7] = cvt_bf16(b.w);
            ((short8*)wb)[v] = o;
        }
        for (size_t v = i0; v < 65536u; v += stride) {
            float4 a = ((const float4*)x)[v * 2];
            float4 b = ((const float4*)x)[v * 2 + 1];
            short8 o;
            o[0] = cvt_bf16(a.x); o[1] = cvt_bf16(a.y); o[2] = cvt_bf16(a.z); o[3] = cvt_bf16(a.w);
            o[4] = cvt_bf16(b.x); o[5] = cvt_bf16(b.y); o[6] = cvt_bf16(b.z); o[7] = cvt_bf16(b.w);
            ((short8*)xb)[v] = o;
        }
    } else {
        const int row = blockIdx.x - 2048;  // 0..255
        if (row == 255) {
            ((unsigned*)(neb + 255 * 512))[tid] = 0u;  // pad row = zeros
            return;
        }
        const float2* nr = (const float2*)(ne + (size_t)row * 512);
        float2 a = nr[tid];  // elems 2t, 2t+1 (coalesced)
        red[tid] = a.x * a.x + a.y * a.y;
        __syncthreads();
        #pragma unroll
        for (int s = 128; s > 0; s >>= 1) {
            if (tid < s) red[tid] += red[tid + s];
            __syncthreads();
        }
        float inv = rsqrtf(red[0]);
        unsigned lo = (unsigned short)cvt_bf16(a.x * inv);
        unsigned hi = (unsigned short)cvt_bf16(a.y * inv);
        ((unsigned*)(neb + (size_t)row * 512))[tid] = lo | (hi << 16);
    }
}

// ---------------------------------------------------------------------------
// Kernel 2: sim GEMM: out1[b,k] = sigmoid(xb[b,:]·neb[k,:]). M=1024,N=255,K=512.
// Block tile 64x64, grid = 16 mt x 4 nt = 64 blocks, 4 waves.
// ---------------------------------------------------------------------------
__global__ __launch_bounds__(256) void simgemm_kernel(const short* __restrict__ xb,
                                                      const short* __restrict__ neb,
                                                      float* __restrict__ out1) {
    __shared__ __align__(16) short Ald[512 * 8];  // 64x64 bf16 = 8 KB
    __shared__ __align__(16) short Bld[512 * 8];
    const int tid = threadIdx.x;
    const int lane = tid & 63, wave = tid >> 6;
    const int q = lane >> 4, r = lane & 15;
    const int mt = blockIdx.x >> 2;  // 0..15
    const int nt = blockIdx.x & 3;   // 0..3

    f32x4 acc[4];
    #pragma unroll
    for (int nf = 0; nf < 4; ++nf) acc[nf] = (f32x4){0.f, 0.f, 0.f, 0.f};

    const bf16x8* Av = (const bf16x8*)Ald;
    const bf16x8* Bv = (const bf16x8*)Bld;

    for (int kb = 0; kb < 8; ++kb) {
        __syncthreads();
        #pragma unroll
        for (int j = 0; j < 2; ++j) {
            int ph = j * 256 + tid, rr = ph >> 3, g = (ph & 7) ^ (rr & 7);
            GLD(xb + ((size_t)(mt * 64 + rr) * D_ + kb * 64 + g * 8), Ald + ph * 8);
        }
        #pragma unroll
        for (int j = 0; j < 2; ++j) {
            int ph = j * 256 + tid, cc = ph >> 3, g = (ph & 7) ^ (cc & 7);
            GLD(neb + ((size_t)(nt * 64 + cc) * D_ + kb * 64 + g * 8), Bld + ph * 8);
        }
        __syncthreads();
        #pragma unroll
        for (int ks = 0; ks < 2; ++ks) {
            const int g = ks * 4 + q;
            int rl = wave * 16 + r;
            bf16x8 af = Av[rl * 8 + (g ^ (rl & 7))];
            #pragma unroll
            for (int nf = 0; nf < 4; ++nf) {
                int cl = nf * 16 + r;
                bf16x8 bfr = Bv[cl * 8 + (g ^ (cl & 7))];
                acc[nf] = __builtin_amdgcn_mfma_f32_16x16x32_bf16(af, bfr, acc[nf], 0, 0, 0);
            }
        }
    }
    #pragma unroll
    for (int nf = 0; nf < 4; ++nf) {
        int gcol = nt * 64 + nf * 16 + r;
        if (gcol < K_) {
            #pragma unroll
            for (int i = 0; i < 4; ++i) {
                int grow = mt * 64 + wave * 16 + q * 4 + i;
                out1[(size_t)grow * K_ + gcol] = 1.f / (1.f + __expf(-acc[nf][i]));
            }
        }
    }
}

// ---------------------------------------------------------------------------
// Kernel 3: leaf probabilities from out1 (sigmoids). Block = batch row.
// ---------------------------------------------------------------------------
__global__ __launch_bounds__(256) void leafprob_kernel(const float* __restrict__ out1,
                                                       float* __restrict__ p_ws) {
    __shared__ float ss[K_];
    const int b = blockIdx.x, t = threadIdx.x;
    if (t < K_) ss[t] = out1[(size_t)b * K_ + t];
    __syncthreads();
    float prob = 1.f;
    int node = 0;
    #pragma unroll
    for (int d = 0; d < 8; ++d) {
        int bit = (t >> (7 - d)) & 1;
        float s = ss[node];
        prob *= bit ? (1.f - s) : s;
        node = 2 * node + 1 + bit;
    }
    p_ws[(size_t)b * L_ + t] = prob;
}

// ---------------------------------------------------------------------------
// Kernel 4: main GEMM. Block tile 128 rows x 2 leaves (80 cols each), BK=64.
// Grid = mt(8) x lp(128) = 1024 blocks = 4 blocks/CU; blockIdx = mt*128+lp
// so XCD = lp%8 (8 m-tiles sharing a B slab land on one XCD; 2.5 MB B/XCD).
// Register structure = round-1's proven 120-VGPR shape: li-outer loop,
// dec[2][5] per leaf + outacc[2][5] fold (fits __launch_bounds__(256,4)'s
// 128-VGPR cap; the flat dec[2][10] version did not -> round-2 regression).
// ---------------------------------------------------------------------------
__global__ __launch_bounds__(256, 4) void gemm_kernel(const short* __restrict__ xb,
                                                      const short* __restrict__ wb,
                                                      const float* __restrict__ p,
                                                      const float* __restrict__ lb,
                                                      float* __restrict__ partial) {
    __shared__ __align__(16) short Ald[1024 * 8];  // 128x64 bf16 = 16 KB
    __shared__ __align__(16) short Bld[640 * 8];   // 80x64 bf16 = 10 KB
    __shared__ float p_ld[128][2];
    __shared__ float b_ld[160];

    const int tid = threadIdx.x;
    const int lane = tid & 63, wave = tid >> 6;
    const int q = lane >> 4, r = lane & 15;
    const int wrow = wave * 32;
    const int lp = blockIdx.x & 127;
    const int mt = blockIdx.x >> 7;

    if (tid < 128) {
        p_ld[tid][0] = p[(size_t)(mt * 128 + tid) * L_ + 2 * lp];
        p_ld[tid][1] = p[(size_t)(mt * 128 + tid) * L_ + 2 * lp + 1];
    }
    if (tid < 160) b_ld[tid] = lb[lp * 160 + tid];

    f32x4 outacc[2][5];
    #pragma unroll
    for (int mf = 0; mf < 2; ++mf)
        #pragma unroll
        for (int nf = 0; nf < 5; ++nf)
            outacc[mf][nf] = (f32x4){0.f, 0.f, 0.f, 0.f};

    const bf16x8* Av = (const bf16x8*)Ald;
    const bf16x8* Bv = (const bf16x8*)Bld;

    for (int li = 0; li < 2; ++li) {
        const int l = lp * 2 + li;
        f32x4 dec[2][5];
        #pragma unroll
        for (int mf = 0; mf < 2; ++mf)
            #pragma unroll
            for (int nf = 0; nf < 5; ++nf)
                dec[mf][nf] = (f32x4){0.f, 0.f, 0.f, 0.f};

        for (int kb = 0; kb < 8; ++kb) {
            __syncthreads();  // previous compute done before overwriting tiles
            // stage A: 1024 granules, 4 per thread
            #pragma unroll
            for (int j = 0; j < 4; ++j) {
                int ph = j * 256 + tid;
                int rr = ph >> 3;
                int g  = (ph & 7) ^ (rr & 7);
                GLD(xb + ((size_t)(mt * 128 + rr) * D_ + kb * 64 + g * 8), Ald + ph * 8);
            }
            // stage B: 640 granules (80 rows of W_l)
            #pragma unroll
            for (int j = 0; j < 2; ++j) {
                int ph = j * 256 + tid;
                int cc = ph >> 3;
                int g  = (ph & 7) ^ (cc & 7);
                GLD(wb + ((size_t)(l * C_ + cc) * D_ + kb * 64 + g * 8), Bld + ph * 8);
            }
            if (tid < 128) {  // wave-uniform: waves 0,1 only
                int ph = 512 + tid;
                int cc = ph >> 3;
                int g  = (ph & 7) ^ (cc & 7);
                GLD(wb + ((size_t)(l * C_ + cc) * D_ + kb * 64 + g * 8), Bld + ph * 8);
            }
            __syncthreads();  // drains vmcnt(0): global_load_lds complete

            #pragma unroll
            for (int ks = 0; ks < 2; ++ks) {
                const int g = ks * 4 + q;
                bf16x8 af[2], bfr[5];
                #pragma unroll
                for (int mf = 0; mf < 2; ++mf) {
                    int rl = wrow + mf * 16 + r;
                    af[mf] = Av[rl * 8 + (g ^ (rl & 7))];
                }
                #pragma unroll
                for (int nf = 0; nf < 5; ++nf) {
                    int cl = nf * 16 + r;
                    bfr[nf] = Bv[cl * 8 + (g ^ (cl & 7))];
                }
                #pragma unroll
                for (int mf = 0; mf < 2; ++mf)
                    #pragma unroll
                    for (int nf = 0; nf < 5; ++nf)
                        dec[mf][nf] = __builtin_amdgcn_mfma_f32_16x16x32_bf16(
                            af[mf], bfr[nf], dec[mf][nf], 0, 0, 0);
            }
        }

        // fp32 fold: outacc += p[row,li] * (dec + bias[col,li])
        #pragma unroll
        for (int mf = 0; mf < 2; ++mf) {
            #pragma unroll
            for (int nf = 0; nf < 5; ++nf) {
                float bv = b_ld[li * 80 + nf * 16 + r];
                #pragma unroll
                for (int i = 0; i < 4; ++i) {
                    int row = wrow + mf * 16 + q * 4 + i;
                    outacc[mf][nf][i] += p_ld[row][li] * (dec[mf][nf][i] + bv);
                }
            }
        }
    }

    // store partials: partial[lp][1024 rows][80 cols], this block owns 128 rows
    const size_t rbase = (size_t)lp * B_ + mt * 128;
    #pragma unroll
    for (int mf = 0; mf < 2; ++mf)
        #pragma unroll
        for (int nf = 0; nf < 5; ++nf)
            #pragma unroll
            for (int i = 0; i < 4; ++i) {
                int row = wrow + mf * 16 + q * 4 + i;
                int col = nf * 16 + r;
                partial[(rbase + row) * C_ + col] = outacc[mf][nf][i];
            }
}

// ---------------------------------------------------------------------------
// Kernel 5: reduce 128 lp partials -> out0 (1024x80), float4 per thread
// ---------------------------------------------------------------------------
__global__ __launch_bounds__(256) void reduce_kernel(const float* __restrict__ partial,
                                                     float* __restrict__ out0) {
    int idx = blockIdx.x * 256 + threadIdx.x;  // < 20480 float4s
    const float4* p4 = (const float4*)partial;
    float4 s = {0.f, 0.f, 0.f, 0.f};
    #pragma unroll 8
    for (int j = 0; j < 128; ++j) {
        float4 v = p4[(size_t)j * (B_ * C_ / 4) + idx];
        s.x += v.x; s.y += v.y; s.z += v.z; s.w += v.w;
    }
    ((float4*)out0)[idx] = s;
}

// ---------------------------------------------------------------------------
extern "C" void kernel_launch(void* const* d_in, const int* in_sizes, int n_in,
                              void* d_out, int out_size, void* d_ws, size_t ws_size,
                              hipStream_t stream) {
    const float* x  = (const float*)d_in[0];  // 1024x512
    const float* ne = (const float*)d_in[1];  // 255x512
    const float* lW = (const float*)d_in[2];  // 20480x512
    const float* lb = (const float*)d_in[3];  // 20480
    // d_in[4] res_path: deterministic structure, traversed directly

    float* out0 = (float*)d_out;            // 1024x80
    float* out1 = out0 + (size_t)B_ * C_;   // 1024x255

    char* ws = (char*)d_ws;
    short* xb      = (short*)ws;                            // 1 MB
    short* neb     = (short*)(ws + (1u << 20));             // 256 KB (256x512 bf16)
    float* p_ws    = (float*)(ws + (1u << 20) + (1u << 18)); // 1 MB
    short* wb      = (short*)(ws + (9u << 18));             // 2.25 MB offset, 20 MB
    float* partial = (float*)(ws + (24u << 20));            // 40 MB (128x1024x80 fp32)

    convert_kernel<<<2304, 256, 0, stream>>>(lW, x, ne, wb, xb, neb);
    simgemm_kernel<<<64, 256, 0, stream>>>(xb, neb, out1);
    leafprob_kernel<<<B_, 256, 0, stream>>>(out1, p_ws);
    gemm_kernel<<<1024, 256, 0, stream>>>(xb, wb, p_ws, lb, partial);
    reduce_kernel<<<B_ * C_ / 1024, 256, 0, stream>>>(partial, out0);
}

// Round 4
// 136.573 us; speedup vs baseline: 1.3730x; 1.3730x over previous
//
#include <hip/hip_runtime.h>
#include <stdint.h>

// Problem constants
#define B_  1024
#define D_  512
#define K_  255
#define L_  256
#define C_  80

typedef __attribute__((ext_vector_type(8))) short bf16x8;
typedef __attribute__((ext_vector_type(4))) float f32x4;
typedef __attribute__((ext_vector_type(8))) short short8;

// async global->LDS, 16B per lane; dst must be wave-uniform base + lane*16.
#define GLD(gsrc, ldst) \
  __builtin_amdgcn_global_load_lds((const __attribute__((address_space(1))) void*)(gsrc), \
                                   (__attribute__((address_space(3))) void*)(ldst), 16, 0, 0)

__device__ __forceinline__ short cvt_bf16(float f) {
    unsigned u = __float_as_uint(f);
    u += 0x7FFFu + ((u >> 16) & 1u);
    return (short)(u >> 16);
}

// ---------------------------------------------------------------------------
// Kernel 1: convert W (20480x512) + x (1024x512) fp32->bf16, AND normalize
// ne rows -> bf16 neb (256 rows; row 255 zeroed).
// ---------------------------------------------------------------------------
__global__ __launch_bounds__(256) void convert_kernel(const float* __restrict__ w,
                                                      const float* __restrict__ x,
                                                      const float* __restrict__ ne,
                                                      short* __restrict__ wb,
                                                      short* __restrict__ xb,
                                                      short* __restrict__ neb) {
    __shared__ float red[256];
    const int tid = threadIdx.x;
    if (blockIdx.x < 2048) {
        size_t i0 = (size_t)blockIdx.x * 256 + tid;
        const size_t stride = 2048u * 256u;
        for (size_t v = i0; v < 1310720u; v += stride) {
            float4 a = ((const float4*)w)[v * 2];
            float4 b = ((const float4*)w)[v * 2 + 1];
            short8 o;
            o[0] = cvt_bf16(a.x); o[1] = cvt_bf16(a.y); o[2] = cvt_bf16(a.z); o[3] = cvt_bf16(a.w);
            o[4] = cvt_bf16(b.x); o[5] = cvt_bf16(b.y); o[6] = cvt_bf16(b.z); o[7] = cvt_bf16(b.w);
            ((short8*)wb)[v] = o;
        }
        for (size_t v = i0; v < 65536u; v += stride) {
            float4 a = ((const float4*)x)[v * 2];
            float4 b = ((const float4*)x)[v * 2 + 1];
            short8 o;
            o[0] = cvt_bf16(a.x); o[1] = cvt_bf16(a.y); o[2] = cvt_bf16(a.z); o[3] = cvt_bf16(a.w);
            o[4] = cvt_bf16(b.x); o[5] = cvt_bf16(b.y); o[6] = cvt_bf16(b.z); o[7] = cvt_bf16(b.w);
            ((short8*)xb)[v] = o;
        }
    } else {
        const int row = blockIdx.x - 2048;  // 0..255
        if (row == 255) {
            ((unsigned*)(neb + 255 * 512))[tid] = 0u;  // pad row = zeros
            return;
        }
        const float2* nr = (const float2*)(ne + (size_t)row * 512);
        float2 a = nr[tid];
        red[tid] = a.x * a.x + a.y * a.y;
        __syncthreads();
        #pragma unroll
        for (int s = 128; s > 0; s >>= 1) {
            if (tid < s) red[tid] += red[tid + s];
            __syncthreads();
        }
        float inv = rsqrtf(red[0]);
        unsigned lo = (unsigned short)cvt_bf16(a.x * inv);
        unsigned hi = (unsigned short)cvt_bf16(a.y * inv);
        ((unsigned*)(neb + (size_t)row * 512))[tid] = lo | (hi << 16);
    }
}

// ---------------------------------------------------------------------------
// Kernel 2: sim GEMM: out1[b,k] = sigmoid(xb[b,:]·neb[k,:]). 64x64 tiles.
// ---------------------------------------------------------------------------
__global__ __launch_bounds__(256) void simgemm_kernel(const short* __restrict__ xb,
                                                      const short* __restrict__ neb,
                                                      float* __restrict__ out1) {
    __shared__ __align__(16) short Ald[512 * 8];
    __shared__ __align__(16) short Bld[512 * 8];
    const int tid = threadIdx.x;
    const int lane = tid & 63, wave = tid >> 6;
    const int q = lane >> 4, r = lane & 15;
    const int mt = blockIdx.x >> 2;
    const int nt = blockIdx.x & 3;

    f32x4 acc[4];
    #pragma unroll
    for (int nf = 0; nf < 4; ++nf) acc[nf] = (f32x4){0.f, 0.f, 0.f, 0.f};

    const bf16x8* Av = (const bf16x8*)Ald;
    const bf16x8* Bv = (const bf16x8*)Bld;

    for (int kb = 0; kb < 8; ++kb) {
        __syncthreads();
        #pragma unroll
        for (int j = 0; j < 2; ++j) {
            int ph = j * 256 + tid, rr = ph >> 3, g = (ph & 7) ^ (rr & 7);
            GLD(xb + ((size_t)(mt * 64 + rr) * D_ + kb * 64 + g * 8), Ald + ph * 8);
        }
        #pragma unroll
        for (int j = 0; j < 2; ++j) {
            int ph = j * 256 + tid, cc = ph >> 3, g = (ph & 7) ^ (cc & 7);
            GLD(neb + ((size_t)(nt * 64 + cc) * D_ + kb * 64 + g * 8), Bld + ph * 8);
        }
        __syncthreads();
        #pragma unroll
        for (int ks = 0; ks < 2; ++ks) {
            const int g = ks * 4 + q;
            int rl = wave * 16 + r;
            bf16x8 af = Av[rl * 8 + (g ^ (rl & 7))];
            #pragma unroll
            for (int nf = 0; nf < 4; ++nf) {
                int cl = nf * 16 + r;
                bf16x8 bfr = Bv[cl * 8 + (g ^ (cl & 7))];
                acc[nf] = __builtin_amdgcn_mfma_f32_16x16x32_bf16(af, bfr, acc[nf], 0, 0, 0);
            }
        }
    }
    #pragma unroll
    for (int nf = 0; nf < 4; ++nf) {
        int gcol = nt * 64 + nf * 16 + r;
        if (gcol < K_) {
            #pragma unroll
            for (int i = 0; i < 4; ++i) {
                int grow = mt * 64 + wave * 16 + q * 4 + i;
                out1[(size_t)grow * K_ + gcol] = 1.f / (1.f + __expf(-acc[nf][i]));
            }
        }
    }
}

// ---------------------------------------------------------------------------
// Kernel 3: leaf probabilities from out1 sigmoids. Block = batch row.
// ---------------------------------------------------------------------------
__global__ __launch_bounds__(256) void leafprob_kernel(const float* __restrict__ out1,
                                                       float* __restrict__ p_ws) {
    __shared__ float ss[K_];
    const int b = blockIdx.x, t = threadIdx.x;
    if (t < K_) ss[t] = out1[(size_t)b * K_ + t];
    __syncthreads();
    float prob = 1.f;
    int node = 0;
    #pragma unroll
    for (int d = 0; d < 8; ++d) {
        int bit = (t >> (7 - d)) & 1;
        float s = ss[node];
        prob *= bit ? (1.f - s) : s;
        node = 2 * node + 1 + bit;
    }
    p_ws[(size_t)b * L_ + t] = prob;
}

// ---------------------------------------------------------------------------
// Kernel 4: main GEMM, BK=128. Block tile 128 rows x 80 cols, 4 leaves/block.
// Grid = mt(8) x lc(64) = 512 blocks, blockIdx = mt*64+lc -> XCD = lc%8
// (the 8 m-tiles sharing a B slab co-resident on one XCD; ~2.6 MB B/XCD).
// Per leaf: 4 kb-stages of K=128 -> 40 MFMA/wave per barrier (2x round 1).
// Register shape = round-1's proven no-spill layout; __launch_bounds__(256,2)
// ONLY — (256,4) forced VGPR=64 + 145 MB scratch spills in round 3.
// LDS: A 32 KB + B 20 KB = 54 KB -> 2 blocks/CU.
// ---------------------------------------------------------------------------
__global__ __launch_bounds__(256, 2) void gemm_kernel(const short* __restrict__ xb,
                                                      const short* __restrict__ wb,
                                                      const float* __restrict__ p,
                                                      const float* __restrict__ lb,
                                                      float* __restrict__ partial) {
    __shared__ __align__(16) short Ald[2048 * 8];  // 128 rows x 16 granules = 32 KB
    __shared__ __align__(16) short Bld[1280 * 8];  // 80 rows x 16 granules = 20 KB
    __shared__ float p_ld[128][4];
    __shared__ float b_ld[320];

    const int tid = threadIdx.x;
    const int lane = tid & 63, wave = tid >> 6;
    const int q = lane >> 4, r = lane & 15;
    const int wrow = wave * 32;
    const int lc = blockIdx.x & 63;   // 64 l-chunks of 4 leaves
    const int mt = blockIdx.x >> 6;   // 8 m-tiles

    if (tid < 128) {
        #pragma unroll
        for (int li = 0; li < 4; ++li)
            p_ld[tid][li] = p[(size_t)(mt * 128 + tid) * L_ + 4 * lc + li];
    }
    {
        int c = tid;
        if (c < 320) b_ld[c] = lb[lc * 320 + c];
        if (tid < 64) b_ld[256 + tid] = lb[lc * 320 + 256 + tid];
    }

    f32x4 outacc[2][5];
    #pragma unroll
    for (int mf = 0; mf < 2; ++mf)
        #pragma unroll
        for (int nf = 0; nf < 5; ++nf)
            outacc[mf][nf] = (f32x4){0.f, 0.f, 0.f, 0.f};

    const bf16x8* Av = (const bf16x8*)Ald;
    const bf16x8* Bv = (const bf16x8*)Bld;

    for (int li = 0; li < 4; ++li) {
        const int l = lc * 4 + li;
        f32x4 dec[2][5];
        #pragma unroll
        for (int mf = 0; mf < 2; ++mf)
            #pragma unroll
            for (int nf = 0; nf < 5; ++nf)
                dec[mf][nf] = (f32x4){0.f, 0.f, 0.f, 0.f};

        for (int kb = 0; kb < 4; ++kb) {  // 4 stages of K=128
            __syncthreads();  // previous compute done before overwriting tiles
            // stage A: 2048 granules (128 rows x 16), 8 per thread
            #pragma unroll
            for (int j = 0; j < 8; ++j) {
                int ph = j * 256 + tid;
                int rr = ph >> 4;
                int g  = (ph & 15) ^ (rr & 15);
                GLD(xb + ((size_t)(mt * 128 + rr) * D_ + kb * 128 + g * 8), Ald + ph * 8);
            }
            // stage B: 1280 granules (80 rows x 16), 5 per thread
            #pragma unroll
            for (int j = 0; j < 5; ++j) {
                int ph = j * 256 + tid;
                int cc = ph >> 4;
                int g  = (ph & 15) ^ (cc & 15);
                GLD(wb + ((size_t)(l * C_ + cc) * D_ + kb * 128 + g * 8), Bld + ph * 8);
            }
            __syncthreads();  // drains vmcnt(0): global_load_lds complete

            #pragma unroll
            for (int ks = 0; ks < 4; ++ks) {  // 4 K=32 slices
                const int g = ks * 4 + q;
                bf16x8 af[2], bfr[5];
                #pragma unroll
                for (int mf = 0; mf < 2; ++mf) {
                    int rl = wrow + mf * 16 + r;
                    af[mf] = Av[rl * 16 + (g ^ (rl & 15))];
                }
                #pragma unroll
                for (int nf = 0; nf < 5; ++nf) {
                    int cl = nf * 16 + r;
                    bfr[nf] = Bv[cl * 16 + (g ^ (cl & 15))];
                }
                #pragma unroll
                for (int mf = 0; mf < 2; ++mf)
                    #pragma unroll
                    for (int nf = 0; nf < 5; ++nf)
                        dec[mf][nf] = __builtin_amdgcn_mfma_f32_16x16x32_bf16(
                            af[mf], bfr[nf], dec[mf][nf], 0, 0, 0);
            }
        }

        // fp32 fold: outacc += p[row,li] * (dec + bias[col,li])
        #pragma unroll
        for (int mf = 0; mf < 2; ++mf) {
            #pragma unroll
            for (int nf = 0; nf < 5; ++nf) {
                float bv = b_ld[li * 80 + nf * 16 + r];
                #pragma unroll
                for (int i = 0; i < 4; ++i) {
                    int row = wrow + mf * 16 + q * 4 + i;
                    outacc[mf][nf][i] += p_ld[row][li] * (dec[mf][nf][i] + bv);
                }
            }
        }
    }

    // store partials: partial[lc][1024 rows][80 cols], this block owns 128 rows
    const size_t rbase = (size_t)lc * B_ + mt * 128;
    #pragma unroll
    for (int mf = 0; mf < 2; ++mf)
        #pragma unroll
        for (int nf = 0; nf < 5; ++nf)
            #pragma unroll
            for (int i = 0; i < 4; ++i) {
                int row = wrow + mf * 16 + q * 4 + i;
                int col = nf * 16 + r;
                partial[(rbase + row) * C_ + col] = outacc[mf][nf][i];
            }
}

// ---------------------------------------------------------------------------
// Kernel 5: reduce 64 lc partials -> out0 (1024x80), float4 per thread
// ---------------------------------------------------------------------------
__global__ __launch_bounds__(256) void reduce_kernel(const float* __restrict__ partial,
                                                     float* __restrict__ out0) {
    int idx = blockIdx.x * 256 + threadIdx.x;  // < 20480 float4s
    const float4* p4 = (const float4*)partial;
    float4 s = {0.f, 0.f, 0.f, 0.f};
    #pragma unroll 8
    for (int j = 0; j < 64; ++j) {
        float4 v = p4[(size_t)j * (B_ * C_ / 4) + idx];
        s.x += v.x; s.y += v.y; s.z += v.z; s.w += v.w;
    }
    ((float4*)out0)[idx] = s;
}

// ---------------------------------------------------------------------------
extern "C" void kernel_launch(void* const* d_in, const int* in_sizes, int n_in,
                              void* d_out, int out_size, void* d_ws, size_t ws_size,
                              hipStream_t stream) {
    const float* x  = (const float*)d_in[0];  // 1024x512
    const float* ne = (const float*)d_in[1];  // 255x512
    const float* lW = (const float*)d_in[2];  // 20480x512
    const float* lb = (const float*)d_in[3];  // 20480
    // d_in[4] res_path: deterministic structure, traversed directly

    float* out0 = (float*)d_out;            // 1024x80
    float* out1 = out0 + (size_t)B_ * C_;   // 1024x255

    char* ws = (char*)d_ws;
    short* xb      = (short*)ws;                             // 1 MB
    short* neb     = (short*)(ws + (1u << 20));              // 256 KB
    float* p_ws    = (float*)(ws + (1u << 20) + (1u << 18)); // 1 MB
    short* wb      = (short*)(ws + (9u << 18));              // 20 MB @ 2.25 MB
    float* partial = (float*)(ws + (24u << 20));             // 21 MB (64x1024x80)

    convert_kernel<<<2304, 256, 0, stream>>>(lW, x, ne, wb, xb, neb);
    simgemm_kernel<<<64, 256, 0, stream>>>(xb, neb, out1);
    leafprob_kernel<<<B_, 256, 0, stream>>>(out1, p_ws);
    gemm_kernel<<<512, 256, 0, stream>>>(xb, wb, p_ws, lb, partial);
    reduce_kernel<<<B_ * C_ / 1024, 256, 0, stream>>>(partial, out0);
}